// Round 2
// baseline (436.014 us; speedup 1.0000x reference)
//
#include <hip/hip_runtime.h>
#include <math.h>

// Problem constants
constexpr int CB = 8;      // batch
constexpr int CS = 1024;   // seq
constexpr int CD = 512;    // model dim
constexpr int CH = 8;      // heads
constexpr int CHD = 64;    // head dim
constexpr int CDFF = 2048; // ffn dim
constexpr int NROW = CB * CS;

typedef unsigned short u16;
typedef unsigned int u32;
typedef __attribute__((ext_vector_type(8))) short short8;
typedef __attribute__((ext_vector_type(8))) unsigned short ushort8v;
typedef __attribute__((ext_vector_type(4))) float floatx4;

__device__ inline u16 f2bf(float f) {
    union { float f; unsigned u; } v; v.f = f;
    unsigned u = v.u + 0x7FFFu + ((v.u >> 16) & 1u);  // RNE
    return (u16)(u >> 16);
}
__device__ inline float bf2f(u16 h) {
    union { unsigned u; float f; } v; v.u = ((unsigned)h) << 16;
    return v.f;
}

// async global->LDS, 16B per lane; LDS dest is wave-uniform base + lane*16
__device__ inline void gload16(const u16* g, u16* l) {
    __builtin_amdgcn_global_load_lds(
        (const __attribute__((address_space(1))) u32*)g,
        (__attribute__((address_space(3))) u32*)l, 16, 0, 0);
}

// ---------------------------------------------------------------------------
// LayerNorm (+ optional embedding add). One block per row, 256 threads.
// ---------------------------------------------------------------------------
__global__ __launch_bounds__(256) void ln_kernel(
    const float* __restrict__ x, const int* __restrict__ ids,
    const float* __restrict__ emb,
    const float* __restrict__ g, const float* __restrict__ beta,
    float* __restrict__ xr_out, u16* __restrict__ xn_out)
{
    __shared__ float red1[4], red2[4];
    __shared__ float mu_s, ri_s;
    int row = blockIdx.x;
    int tid = threadIdx.x;
    int d0 = tid * 2;
    const float* xrow = x + (size_t)row * CD;
    float2 xv = *(const float2*)(xrow + d0);
    float v0 = xv.x, v1 = xv.y;
    if (emb) {
        int id = ids[row];
        float2 ev = *(const float2*)(emb + (size_t)id * CD + d0);
        v0 += ev.x; v1 += ev.y;
    }
    float s1 = v0 + v1;
    float s2 = v0 * v0 + v1 * v1;
    for (int off = 32; off > 0; off >>= 1) {
        s1 += __shfl_down(s1, off, 64);
        s2 += __shfl_down(s2, off, 64);
    }
    int wave = tid >> 6;
    if ((tid & 63) == 0) { red1[wave] = s1; red2[wave] = s2; }
    __syncthreads();
    if (tid == 0) {
        float t1 = red1[0] + red1[1] + red1[2] + red1[3];
        float t2 = red2[0] + red2[1] + red2[2] + red2[3];
        float mu = t1 / CD;
        float var = t2 / CD - mu * mu;
        mu_s = mu;
        ri_s = rsqrtf(var + 1e-5f);
    }
    __syncthreads();
    float mu = mu_s, ri = ri_s;
    if (xr_out) {
        float2 o; o.x = v0; o.y = v1;
        *(float2*)(xr_out + (size_t)row * CD + d0) = o;
    }
    float2 gv = *(const float2*)(g + d0);
    float2 bv = *(const float2*)(beta + d0);
    float n0 = (v0 - mu) * ri * gv.x + bv.x;
    float n1 = (v1 - mu) * ri * gv.y + bv.y;
    u32 pk = (u32)f2bf(n0) | ((u32)f2bf(n1) << 16);
    *(u32*)(xn_out + (size_t)row * CD + d0) = pk;
}

// ---------------------------------------------------------------------------
// fp32 -> bf16 elementwise convert (weights), 8 elems/thread
// ---------------------------------------------------------------------------
__global__ __launch_bounds__(256) void conv_kernel(
    const float* __restrict__ src, u16* __restrict__ dst)
{
    size_t i = ((size_t)blockIdx.x * 256 + threadIdx.x) * 8;
    float4 a = *(const float4*)(src + i);
    float4 b = *(const float4*)(src + i + 4);
    ushort8v o;
    o[0] = f2bf(a.x); o[1] = f2bf(a.y); o[2] = f2bf(a.z); o[3] = f2bf(a.w);
    o[4] = f2bf(b.x); o[5] = f2bf(b.y); o[6] = f2bf(b.z); o[7] = f2bf(b.w);
    *(ushort8v*)(dst + i) = o;
}

// ---------------------------------------------------------------------------
// bf16 MFMA GEMM, 128x128 tile (m97 recipe): C = act(A @ W^T + bias)(+res)
// ---------------------------------------------------------------------------
template <int ACT, int RES, int OUTBF>
__global__ __launch_bounds__(256) void gemm_mfma(
    const u16* __restrict__ A, const u16* __restrict__ W,
    const float* __restrict__ bias, const float* __restrict__ res,
    void* __restrict__ Cout, int M, int N, int K)
{
    __shared__ u16 As[128 * 32];
    __shared__ u16 Bs[128 * 32];
    int t = threadIdx.x;
    int lane = t & 63;
    int w = t >> 6;
    int m0 = blockIdx.x * 128;
    int n0 = blockIdx.y * 128;
    int col = lane & 15;
    int quad = lane >> 4;
    int wm = w & 1, wn = w >> 1;

    const u16* ag = A + (size_t)(m0 + (t >> 2)) * K + (t & 3) * 8;
    const u16* ag2 = ag + (size_t)64 * K;
    const u16* bg = W + (size_t)(n0 + (t >> 2)) * K + (t & 3) * 8;
    const u16* bg2 = bg + (size_t)64 * K;
    u16* la = As + w * 512;
    u16* lb = Bs + w * 512;

    floatx4 acc[4][4];
#pragma unroll
    for (int i = 0; i < 4; i++)
#pragma unroll
        for (int j = 0; j < 4; j++) acc[i][j] = (floatx4){0.f, 0.f, 0.f, 0.f};

    for (int kt = 0; kt < K; kt += 32) {
        gload16(ag + kt, la);
        gload16(ag2 + kt, la + 2048);
        gload16(bg + kt, lb);
        gload16(bg2 + kt, lb + 2048);
        __syncthreads();
        short8 af[4], bf[4];
#pragma unroll
        for (int mi = 0; mi < 4; mi++)
            af[mi] = *(const short8*)&As[(wm * 64 + mi * 16 + col) * 32 + quad * 8];
#pragma unroll
        for (int ni = 0; ni < 4; ni++)
            bf[ni] = *(const short8*)&Bs[(wn * 64 + ni * 16 + col) * 32 + quad * 8];
#pragma unroll
        for (int mi = 0; mi < 4; mi++)
#pragma unroll
            for (int ni = 0; ni < 4; ni++)
                acc[mi][ni] = __builtin_amdgcn_mfma_f32_16x16x32_bf16(
                    af[mi], bf[ni], acc[mi][ni], 0, 0, 0);
        __syncthreads();
    }

#pragma unroll
    for (int mi = 0; mi < 4; mi++)
#pragma unroll
        for (int ni = 0; ni < 4; ni++) {
            int c = n0 + wn * 64 + ni * 16 + col;
            float bv = bias[c];
#pragma unroll
            for (int r = 0; r < 4; r++) {
                int m = m0 + wm * 64 + mi * 16 + quad * 4 + r;
                float v = acc[mi][ni][r] + bv;
                if (ACT == 1) v = 0.5f * v * (1.0f + erff(v * 0.70710678118654752f));
                if (RES) v += res[(size_t)m * N + c];
                if (OUTBF) ((u16*)Cout)[(size_t)m * N + c] = f2bf(v);
                else       ((float*)Cout)[(size_t)m * N + c] = v;
            }
        }
}

// ---------------------------------------------------------------------------
// bf16 MFMA GEMM, 64x128 tile — for N=512 layers (512 blocks -> 2/CU)
// ---------------------------------------------------------------------------
template <int ACT, int RES, int OUTBF>
__global__ __launch_bounds__(256) void gemm_mfma64(
    const u16* __restrict__ A, const u16* __restrict__ W,
    const float* __restrict__ bias, const float* __restrict__ res,
    void* __restrict__ Cout, int M, int N, int K)
{
    __shared__ u16 As[64 * 32];
    __shared__ u16 Bs[128 * 32];
    int t = threadIdx.x;
    int lane = t & 63;
    int w = t >> 6;
    int m0 = blockIdx.x * 64;
    int n0 = blockIdx.y * 128;
    int col = lane & 15;
    int quad = lane >> 4;

    const u16* ag = A + (size_t)(m0 + (t >> 2)) * K + (t & 3) * 8;
    const u16* bg = W + (size_t)(n0 + (t >> 2)) * K + (t & 3) * 8;
    const u16* bg2 = bg + (size_t)64 * K;
    u16* la = As + w * 512;
    u16* lb = Bs + w * 512;

    floatx4 acc[4][2];
#pragma unroll
    for (int i = 0; i < 4; i++)
#pragma unroll
        for (int j = 0; j < 2; j++) acc[i][j] = (floatx4){0.f, 0.f, 0.f, 0.f};

    for (int kt = 0; kt < K; kt += 32) {
        gload16(ag + kt, la);
        gload16(bg + kt, lb);
        gload16(bg2 + kt, lb + 2048);
        __syncthreads();
        short8 af[4], bf[2];
#pragma unroll
        for (int mi = 0; mi < 4; mi++)
            af[mi] = *(const short8*)&As[(mi * 16 + col) * 32 + quad * 8];
#pragma unroll
        for (int ni = 0; ni < 2; ni++)
            bf[ni] = *(const short8*)&Bs[(w * 32 + ni * 16 + col) * 32 + quad * 8];
#pragma unroll
        for (int mi = 0; mi < 4; mi++)
#pragma unroll
            for (int ni = 0; ni < 2; ni++)
                acc[mi][ni] = __builtin_amdgcn_mfma_f32_16x16x32_bf16(
                    af[mi], bf[ni], acc[mi][ni], 0, 0, 0);
        __syncthreads();
    }

#pragma unroll
    for (int mi = 0; mi < 4; mi++)
#pragma unroll
        for (int ni = 0; ni < 2; ni++) {
            int c = n0 + w * 32 + ni * 16 + col;
            float bv = bias[c];
#pragma unroll
            for (int r = 0; r < 4; r++) {
                int m = m0 + mi * 16 + quad * 4 + r;
                float v = acc[mi][ni][r] + bv;
                if (ACT == 1) v = 0.5f * v * (1.0f + erff(v * 0.70710678118654752f));
                if (RES) v += res[(size_t)m * N + c];
                if (OUTBF) ((u16*)Cout)[(size_t)m * N + c] = f2bf(v);
                else       ((float*)Cout)[(size_t)m * N + c] = v;
            }
        }
}

// ---------------------------------------------------------------------------
// K repack: qkv [B,S,1536] col-slice -> [b][h][s][64] contiguous (128B rows)
// ---------------------------------------------------------------------------
__global__ __launch_bounds__(256) void kpack_kernel(
    const u16* __restrict__ qkvb, u16* __restrict__ dst, int coff)
{
    size_t i = ((size_t)blockIdx.x * 256 + threadIdx.x) * 8;  // output index
    int d = (int)(i & 63);
    int s = (int)((i >> 6) & (CS - 1));
    int h = (int)((i >> 16) & (CH - 1));
    int b = (int)(i >> 19);
    const u16* src = qkvb + (size_t)(b * CS + s) * 1536 + coff + h * CHD + d;
    *(ushort8v*)(dst + i) = *(const ushort8v*)src;
}

// ---------------------------------------------------------------------------
// V repack: qkv cols 1024.. -> [b][h][S/64][64d][64k] 4KB tiles.
// ---------------------------------------------------------------------------
__global__ __launch_bounds__(256) void vpack_kernel(
    const u16* __restrict__ qkvb, u16* __restrict__ vp)
{
    __shared__ u16 tile[64][72];
    int b = blockIdx.x >> 4;
    int s0 = (blockIdx.x & 15) * 64;
    int h = blockIdx.y;
    int t = threadIdx.x;
    int r = t >> 2;          // load: s-row / store: d-row
    int c0 = (t & 3) * 16;   // load: d chunk / store: key chunk
    const u16* src = qkvb + (size_t)(b * CS + s0 + r) * 1536 + 2 * CD + h * CHD + c0;
    *(ushort8v*)&tile[r][c0] = *(const ushort8v*)src;
    *(ushort8v*)&tile[r][c0 + 8] = *(const ushort8v*)(src + 8);
    __syncthreads();
    u16* dst = vp + (((size_t)(b * CH + h) * 16 + (s0 >> 6)) << 12) + r * 64 + c0;
    ushort8v lo, hi;
#pragma unroll
    for (int j = 0; j < 8; j++) { lo[j] = tile[c0 + j][r]; hi[j] = tile[c0 + 8 + j][r]; }
    *(ushort8v*)dst = lo;
    *(ushort8v*)(dst + 8) = hi;
}

// ---------------------------------------------------------------------------
// attn1: ctx only. One block per (b, head, 16-q-tile) -> 4096 blocks, 256 thr.
// exp(s/8) has no running max => PV accumulation is linear: single-buffered
// S[16][1032] (33.3KB LDS -> 4 blocks/CU), ONE barrier per block, each wave
// owns a 16-d subtile x all 1024 keys in PV (no cross-wave O combine).
// Also emits rowsums L[b][h][q] for attn2.
// ---------------------------------------------------------------------------
__global__ __launch_bounds__(256, 4) void attn1_kernel(
    const u16* __restrict__ qkvb, const u16* __restrict__ kp,
    const u16* __restrict__ vp,
    u16* __restrict__ ctx, float* __restrict__ Lout)
{
    __shared__ u16 S[16][1032];
    __shared__ float rs[4][16];

    int tid = threadIdx.x;
    int lane = tid & 63;
    int w = tid >> 6;          // wave 0..3
    int col = lane & 15;
    int quad = lane >> 4;
    int bid = blockIdx.x;      // ((b*8 + h)*64 + qb)
    int qb = bid & 63;
    int bh = bid >> 6;
    int h = bh & 7;
    int b = bh >> 3;
    int q0 = qb * 16;

    // Q A-fragments (two d-halves) straight from qkv
    const u16* qrow = qkvb + (size_t)(b * CS + q0 + col) * 1536 + h * CHD + quad * 8;
    short8 qa0 = *(const short8*)qrow;
    short8 qa1 = *(const short8*)(qrow + 32);

    // ---- QK: wave w keys [w*256, +256), e = exp(s/8) -> S, rowsum partials
    const u16* kbase = kp + ((size_t)(b * CH + h) * CS + w * 256 + col) * CHD + quad * 8;
    float esum[4] = {0.f, 0.f, 0.f, 0.f};
#pragma unroll
    for (int st = 0; st < 16; st++) {
        const u16* krow = kbase + (size_t)st * (16 * CHD);
        short8 kb0 = *(const short8*)krow;
        short8 kb1 = *(const short8*)(krow + 32);
        floatx4 c = {0.f, 0.f, 0.f, 0.f};
        c = __builtin_amdgcn_mfma_f32_16x16x32_bf16(qa0, kb0, c, 0, 0, 0);
        c = __builtin_amdgcn_mfma_f32_16x16x32_bf16(qa1, kb1, c, 0, 0, 0);
        int key0 = w * 256 + st * 16;
#pragma unroll
        for (int r = 0; r < 4; r++) {
            float e = __expf(c[r] * 0.125f);
            esum[r] += e;
            union { float f; u32 u; } pu; pu.f = e;
            S[quad * 4 + r][key0 + col] = (u16)(pu.u >> 16);  // bf16 trunc
        }
    }
#pragma unroll
    for (int r = 0; r < 4; r++) {
        esum[r] += __shfl_xor(esum[r], 1, 64);
        esum[r] += __shfl_xor(esum[r], 2, 64);
        esum[r] += __shfl_xor(esum[r], 4, 64);
        esum[r] += __shfl_xor(esum[r], 8, 64);
    }
    if (col == 0) {
#pragma unroll
        for (int r = 0; r < 4; r++) rs[w][quad * 4 + r] = esum[r];
    }
    __syncthreads();   // the only barrier: S + rs complete

    // rowsum L -> global (for attn2)
    if (tid < 16) {
        float L = rs[0][tid] + rs[1][tid] + rs[2][tid] + rs[3][tid];
        Lout[(((size_t)b * CH + h) << 10) + q0 + tid] = L;
    }

    // per-lane 1/L for the 4 output rows
    float li[4];
#pragma unroll
    for (int r = 0; r < 4; r++) {
        int row = quad * 4 + r;
        li[r] = 1.0f / (rs[0][row] + rs[1][row] + rs[2][row] + rs[3][row]);
    }

    // ---- PV: wave w owns d-subtile w (16 d-rows), all 1024 keys ----
    floatx4 oc0 = {0.f, 0.f, 0.f, 0.f};
    floatx4 oc1 = {0.f, 0.f, 0.f, 0.f};
    const u16* vtile = vp + (((size_t)(b * CH + h) * 16) << 12)
                       + (w * 16 + col) * 64 + quad * 8;
#pragma unroll
    for (int kt = 0; kt < 16; kt++) {
        short8 pa0 = *(const short8*)&S[col][kt * 64 + quad * 8];
        short8 vb0 = *(const short8*)(vtile + (size_t)kt * 4096);
        oc0 = __builtin_amdgcn_mfma_f32_16x16x32_bf16(pa0, vb0, oc0, 0, 0, 0);
        short8 pa1 = *(const short8*)&S[col][kt * 64 + 32 + quad * 8];
        short8 vb1 = *(const short8*)(vtile + (size_t)kt * 4096 + 32);
        oc1 = __builtin_amdgcn_mfma_f32_16x16x32_bf16(pa1, vb1, oc1, 0, 0, 0);
    }
    u16* cb = ctx + ((size_t)(b * CS) + q0) * CD + h * CHD + w * 16 + col;
#pragma unroll
    for (int r = 0; r < 4; r++)
        cb[(size_t)(quad * 4 + r) * CD] = f2bf((oc0[r] + oc1[r]) * li[r]);
}

// ---------------------------------------------------------------------------
// attn2: head-averaged attention weights. One block per (b, 16-q-tile,
// key-half) -> 1024 blocks, 256 thr / 4 waves, NO LDS, NO barriers.
// Recomputes QK^T per head (8.6 GF total), reads L from attn1, accumulates
// aw in the MFMA C-layout registers (zero cross-lane traffic), writes fp32.
// ---------------------------------------------------------------------------
__global__ __launch_bounds__(256, 4) void attn2_kernel(
    const u16* __restrict__ qkvb, const u16* __restrict__ kp,
    const float* __restrict__ Lin, float* __restrict__ aw_out)
{
    int tid = threadIdx.x;
    int lane = tid & 63;
    int w = tid >> 6;          // wave 0..3
    int col = lane & 15;
    int quad = lane >> 4;
    int bid = blockIdx.x;      // (b*64 + qb)*2 + kh
    int kh = bid & 1;
    int bq = bid >> 1;
    int qb = bq & 63;
    int b = bq >> 6;
    int q0 = qb * 16;
    int k0 = kh * 512 + w * 128;   // this wave's 128-key strip

    float aw[32];
#pragma unroll
    for (int i = 0; i < 32; i++) aw[i] = 0.f;

    for (int h = 0; h < CH; h++) {
        const u16* qrow = qkvb + (size_t)(b * CS + q0 + col) * 1536 + h * CHD + quad * 8;
        short8 qa0 = *(const short8*)qrow;
        short8 qa1 = *(const short8*)(qrow + 32);
        float linv[4];
#pragma unroll
        for (int r = 0; r < 4; r++)
            linv[r] = 0.125f / Lin[(((size_t)b * CH + h) << 10) + q0 + quad * 4 + r];
        const u16* kbase = kp + ((size_t)(b * CH + h) * CS + k0 + col) * CHD + quad * 8;
#pragma unroll
        for (int st = 0; st < 8; st++) {
            const u16* krow = kbase + (size_t)st * (16 * CHD);
            short8 kb0 = *(const short8*)krow;
            short8 kb1 = *(const short8*)(krow + 32);
            floatx4 c = {0.f, 0.f, 0.f, 0.f};
            c = __builtin_amdgcn_mfma_f32_16x16x32_bf16(qa0, kb0, c, 0, 0, 0);
            c = __builtin_amdgcn_mfma_f32_16x16x32_bf16(qa1, kb1, c, 0, 0, 0);
#pragma unroll
            for (int r = 0; r < 4; r++)
                aw[st * 4 + r] += __expf(c[r] * 0.125f) * linv[r];
        }
    }

    // write: lane owns (q = q0+quad*4+r, k = k0 + st*16 + col)
#pragma unroll
    for (int st = 0; st < 8; st++)
#pragma unroll
        for (int r = 0; r < 4; r++) {
            size_t idx = ((size_t)(b * CS) + q0 + quad * 4 + r) * CS + k0 + st * 16 + col;
            aw_out[idx] = aw[st * 4 + r];
        }
}

// ---------------------------------------------------------------------------
extern "C" void kernel_launch(void* const* d_in, const int* in_sizes, int n_in,
                              void* d_out, int out_size, void* d_ws, size_t ws_size,
                              hipStream_t stream)
{
    const float* x    = (const float*)d_in[0];
    const int*   ids  = (const int*)d_in[1];
    const float* emb  = (const float*)d_in[2];
    const float* inw  = (const float*)d_in[3];
    const float* inb  = (const float*)d_in[4];
    const float* ow   = (const float*)d_in[5];
    const float* ob   = (const float*)d_in[6];
    const float* g1   = (const float*)d_in[7];
    const float* be1  = (const float*)d_in[8];
    const float* g2   = (const float*)d_in[9];
    const float* be2  = (const float*)d_in[10];
    const float* w1   = (const float*)d_in[11];
    const float* b1   = (const float*)d_in[12];
    const float* w2   = (const float*)d_in[13];
    const float* b2   = (const float*)d_in[14];

    float* out_x  = (float*)d_out;
    float* out_aw = out_x + (size_t)CB * CS * CD;

    char* p = (char*)d_ws;
    float* xr   = (float*)p; p += (size_t)NROW * CD * 4;
    float* x2   = (float*)p; p += (size_t)NROW * CD * 4;
    u16* xnb    = (u16*)p;   p += (size_t)NROW * CD * 2;
    u16* qkvb   = (u16*)p;   p += (size_t)NROW * 3 * CD * 2;
    u16* ctxb   = (u16*)p;   p += (size_t)NROW * CD * 2;
    u16* hidb   = (u16*)p;   p += (size_t)NROW * CDFF * 2;
    u16* inwb   = (u16*)p;   p += (size_t)3 * CD * CD * 2;
    u16* owb    = (u16*)p;   p += (size_t)CD * CD * 2;
    u16* w1b    = (u16*)p;   p += (size_t)CDFF * CD * 2;
    u16* w2b    = (u16*)p;   p += (size_t)CD * CDFF * 2;
    float* Lbuf = (float*)p; p += (size_t)CB * CH * CS * 4;   // rowsums, 256KB

    // packed K/V alias the hidb region (hidb only becomes live at step 6,
    // after attention has consumed kp/vp): 2 x 8.4MB <= 33.6MB
    constexpr size_t PKELEM = (size_t)CB * CH * CS * CHD;  // 4.19M u16
    u16* kp = hidb;
    u16* vp = hidb + PKELEM;

    dim3 blk(256);
    // 0) weight conversions
    conv_kernel<<<(3 * CD * CD) / 2048, blk, 0, stream>>>(inw, inwb);
    conv_kernel<<<(CD * CD) / 2048, blk, 0, stream>>>(ow, owb);
    conv_kernel<<<(CDFF * CD) / 2048, blk, 0, stream>>>(w1, w1b);
    conv_kernel<<<(CD * CDFF) / 2048, blk, 0, stream>>>(w2, w2b);
    // 1) x+emb, LN1 -> xr fp32, xnb bf16
    ln_kernel<<<NROW, blk, 0, stream>>>(x, ids, emb, g1, be1, xr, xnb);
    // 2) qkv projection (bf16 MFMA, bf16 out)
    gemm_mfma<0, 0, 1><<<dim3(NROW / 128, (3 * CD) / 128), blk, 0, stream>>>(
        xnb, inwb, inb, nullptr, qkvb, NROW, 3 * CD, CD);
    // 3a) K/V repack into attention-friendly layouts
    kpack_kernel<<<(int)(PKELEM / 2048), blk, 0, stream>>>(qkvb, kp, CD);
    vpack_kernel<<<dim3(CB * (CS / 64), CH), blk, 0, stream>>>(qkvb, vp);
    // 3b) attention ctx (one head per block, 4096 blocks) + rowsums
    attn1_kernel<<<CB * CH * (CS / 16), blk, 0, stream>>>(
        qkvb, kp, vp, ctxb, Lbuf);
    // 3c) head-averaged attention weights (1024 blocks, no LDS/barriers)
    attn2_kernel<<<CB * (CS / 16) * 2, blk, 0, stream>>>(
        qkvb, kp, Lbuf, out_aw);
    // 4) out projection + residual -> x2 fp32 (64x128 tiles: 512 blocks)
    gemm_mfma64<0, 1, 0><<<dim3(NROW / 64, CD / 128), blk, 0, stream>>>(
        ctxb, owb, ob, xr, x2, NROW, CD, CD);
    // 5) LN2 -> xnb bf16
    ln_kernel<<<NROW, blk, 0, stream>>>(x2, nullptr, nullptr, g2, be2, nullptr, xnb);
    // 6) FFN up + exact GELU -> hidb bf16
    gemm_mfma<1, 0, 1><<<dim3(NROW / 128, CDFF / 128), blk, 0, stream>>>(
        xnb, w1b, b1, nullptr, hidb, NROW, CDFF, CD);
    // 7) FFN down + bias + residual -> output fp32 (64x128 tiles: 512 blocks)
    gemm_mfma64<0, 1, 0><<<dim3(NROW / 64, CD / 128), blk, 0, stream>>>(
        hidb, w2b, b2, x2, out_x, NROW, CD, CDFF);
}